// Round 2
// baseline (498.006 us; speedup 1.0000x reference)
//
#include <hip/hip_runtime.h>
#include <hip/hip_fp16.h>

// Problem constants: C=64, S=2048, H=512; rows = C*S = 131072
#define HDIM 512

typedef __fp16 fp16x2 __attribute__((ext_vector_type(2)));
typedef _Float16 h8 __attribute__((ext_vector_type(8)));
typedef __attribute__((ext_vector_type(4))) float floatx4;

// raw barrier: LDS-visibility only, no vmem drain (unlike __syncthreads)
__device__ __forceinline__ void lds_barrier() {
  asm volatile("s_waitcnt lgkmcnt(0)\n\ts_barrier" ::: "memory");
}
__device__ __forceinline__ void issue_fence() {  // pin vm-issue order
  asm volatile("" ::: "memory");
}

// ---------------------------------------------------------------------------
// Kernel 1: W fp32 -> fp16 (RTE)
// ---------------------------------------------------------------------------
__global__ __launch_bounds__(256) void prep_w_kernel(
    const float* __restrict__ W, _Float16* __restrict__ wf) {
  int i = (blockIdx.x * 256 + threadIdx.x) * 4;
  float4 f = *(const float4*)(W + i);
  wf[i + 0] = (_Float16)f.x;
  wf[i + 1] = (_Float16)f.y;
  wf[i + 2] = (_Float16)f.z;
  wf[i + 3] = (_Float16)f.w;
}

// ---------------------------------------------------------------------------
// Kernel 2: fused GEMM. BM=128 x BN=512 (full width), BK=32, 8 waves.
// W streamed through a 4-deep global_load_lds ring, dma+x issued BEFORE the
// barrier at distance 2: stage(t)'s register wait for x_t drains dma_t
// (dma_t issued before x_t), and barrier(t) then guarantees ALL waves' dma_t
// landed before any wave computes on it. 12 vmem ops stay in flight at all
// times; vmcnt never drains to 0 inside the loop.
// W read swizzle uses (lrow>>2) so 16 consecutive lanes hit 16 distinct 16B
// slots (round-1's (lrow>>1) variant was 2-way conflicted: 3.1M conflicts).
// ---------------------------------------------------------------------------
#define XS_H (128 * 40)  // x tile, stride padded 32->40 halves (conflict-free)
#define WS_H (512 * 32)  // w tile halves per buffer

__device__ __forceinline__ void issue_w_dma(const _Float16* __restrict__ wf,
                                            _Float16* dst, int kt, int tid,
                                            int widx) {
#pragma unroll
  for (int q = 0; q < 4; ++q) {
    int idx = q * 512 + tid;
    int n = idx >> 2;                       // W row (output col), 0..511
    int src = (idx & 3) ^ ((n >> 2) & 3);   // source-side XOR swizzle (bit fix)
    size_t goff = (size_t)n * HDIM + kt * 32 + src * 8;
    __builtin_amdgcn_global_load_lds(
        (const __attribute__((address_space(1))) void*)(wf + goff),
        (__attribute__((address_space(3))) void*)(dst +
                                                  (q * 512 + widx * 64) * 8),
        16, 0, 0);
  }
}

__global__ __launch_bounds__(512, 2) void gemm_kernel(
    const float* __restrict__ x, const _Float16* __restrict__ wf,
    const float* __restrict__ bias, __half* __restrict__ e,
    float* __restrict__ u_part, float* __restrict__ den_part) {
  __shared__ __align__(16) _Float16 smem[2 * XS_H + 4 * WS_H];  // 151552 B
  _Float16* xs[2] = {smem, smem + XS_H};
  _Float16* wsm = smem + 2 * XS_H;

  const int tid = threadIdx.x;
  const int lane = tid & 63;
  const int widx = tid >> 6;       // 0..7
  const int wave_m = widx >> 2;    // 0..1
  const int wave_n = widx & 3;     // 0..3
  const int lrow = lane & 15, quad = lane >> 4;

  const int bid = blockIdx.x;      // 1024 blocks, 128 rows each
  const int row0 = bid * 128;

  const int xrow = tid >> 2;       // 0..127
  const int xcg = tid & 3;         // 8-float chunk within 32-float K-tile
  const float* xbase = x + (size_t)(row0 + xrow) * HDIM + xcg * 8;

  floatx4 acc[4][8];
#pragma unroll
  for (int i = 0; i < 4; ++i)
#pragma unroll
    for (int j = 0; j < 8; ++j) acc[i][j] = (floatx4){0.f, 0.f, 0.f, 0.f};

  float4 xr[2][2];

  // prologue: dma_0, x_0, dma_1, x_1 (dma before x => drained by x's wait)
  issue_w_dma(wf, wsm + 0 * WS_H, 0, tid, widx);
  issue_fence();
  xr[0][0] = *(const float4*)xbase;
  xr[0][1] = *(const float4*)(xbase + 4);
  issue_fence();
  issue_w_dma(wf, wsm + 1 * WS_H, 1, tid, widx);
  issue_fence();
  xr[1][0] = *(const float4*)(xbase + 32);
  xr[1][1] = *(const float4*)(xbase + 36);
  issue_fence();

  const int chunkB = quad ^ ((lrow >> 2) & 3);  // W read-side swizzle (fixed)

#pragma unroll
  for (int t = 0; t < 16; ++t) {
    // ---- stage x_t (fp32->fp16); compiler waits x_t here, draining dma_t
    {
      float4 a0 = xr[t & 1][0], a1 = xr[t & 1][1];
      union { h8 v8; fp16x2 v2[4]; } u;
      u.v2[0] = __builtin_amdgcn_cvt_pkrtz(a0.x, a0.y);
      u.v2[1] = __builtin_amdgcn_cvt_pkrtz(a0.z, a0.w);
      u.v2[2] = __builtin_amdgcn_cvt_pkrtz(a1.x, a1.y);
      u.v2[3] = __builtin_amdgcn_cvt_pkrtz(a1.z, a1.w);
      *(h8*)&xs[t & 1][xrow * 40 + xcg * 8] = u.v8;
    }
    // ---- issue next loads BEFORE the barrier (dma older than x)
    if (t <= 13) {
      issue_w_dma(wf, wsm + ((t + 2) & 3) * WS_H, t + 2, tid, widx);
      issue_fence();
      const float* gp = xbase + (t + 2) * 32;
      xr[t & 1][0] = *(const float4*)gp;
      xr[t & 1][1] = *(const float4*)(gp + 4);
      issue_fence();
    }
    lds_barrier();  // xs(t) visible AND all waves' dma_t drained (via stage)
    // ---- compute
    const _Float16* xsr = xs[t & 1];
    const _Float16* wcur = wsm + (t & 3) * WS_H;
    h8 a[4], bh[8];
#pragma unroll
    for (int mt = 0; mt < 4; ++mt)
      a[mt] = *(const h8*)&xsr[(wave_m * 64 + mt * 16 + lrow) * 40 + quad * 8];
#pragma unroll
    for (int nt = 0; nt < 8; ++nt)
      bh[nt] =
          *(const h8*)&wcur[(wave_n * 128 + nt * 16 + lrow) * 32 + chunkB * 8];
    __builtin_amdgcn_s_setprio(1);
#pragma unroll
    for (int mt = 0; mt < 4; ++mt)
#pragma unroll
      for (int nt = 0; nt < 8; ++nt)
        acc[mt][nt] = __builtin_amdgcn_mfma_f32_16x16x32_f16(
            a[mt], bh[nt], acc[mt][nt], 0, 0, 0);
    __builtin_amdgcn_s_setprio(0);
  }

  // ---- epilogue: squash + e-write + iteration-1 partials (no atomics) ----
  float* sqp = (float*)smem;        // [4][128]  (reuses xs[0] region)
  float* scs = (float*)smem + 512;  // [128]
  float* upl = (float*)smem + 640;  // [2][512]

  float bias_v[8];
  int colg[8];
#pragma unroll
  for (int nt = 0; nt < 8; ++nt) {
    colg[nt] = wave_n * 128 + nt * 16 + lrow;
    bias_v[nt] = bias[colg[nt]];
  }
#pragma unroll
  for (int mt = 0; mt < 4; ++mt) {
#pragma unroll
    for (int r = 0; r < 4; ++r) {
      float s = 0.f;
#pragma unroll
      for (int nt = 0; nt < 8; ++nt) {
        float yv = acc[mt][nt][r] + bias_v[nt];
        s += yv * yv;
      }
      s += __shfl_xor(s, 1, 64);
      s += __shfl_xor(s, 2, 64);
      s += __shfl_xor(s, 4, 64);
      s += __shfl_xor(s, 8, 64);
      if (lrow == 0)
        sqp[wave_n * 128 + wave_m * 64 + mt * 16 + quad * 4 + r] = s;
    }
  }
  lds_barrier();
  if (tid < 128) {
    float s = sqp[tid] + sqp[128 + tid] + sqp[256 + tid] + sqp[384 + tid];
    scs[tid] = s / ((1.f + s) * sqrtf(s + 1e-7f));
  }
  lds_barrier();

  float up[8] = {0.f, 0.f, 0.f, 0.f, 0.f, 0.f, 0.f, 0.f};
#pragma unroll
  for (int mt = 0; mt < 4; ++mt) {
#pragma unroll
    for (int r = 0; r < 4; ++r) {
      int row_local = wave_m * 64 + mt * 16 + quad * 4 + r;
      float scv = scs[row_local];
      __half* erow = e + (size_t)(row0 + row_local) * HDIM;
#pragma unroll
      for (int nt = 0; nt < 8; ++nt) {
        float ev = (acc[mt][nt][r] + bias_v[nt]) * scv;
        erow[colg[nt]] = __float2half(ev);
        up[nt] += ev;
      }
    }
  }
#pragma unroll
  for (int nt = 0; nt < 8; ++nt) {
    float v = up[nt];
    v += __shfl_xor(v, 16, 64);
    v += __shfl_xor(v, 32, 64);
    if (quad == 0) upl[wave_m * 512 + colg[nt]] = v;
  }
  lds_barrier();
  // unified u_part layout: [cap][32][512]; gemm fills chunks 0..15
  u_part[(size_t)((bid >> 4) * 32 + (bid & 15)) * HDIM + tid] =
      upl[tid] + upl[512 + tid];
  if (tid == 0) den_part[(bid >> 4) * 32 + (bid & 15)] = 128.0f;
}

// ---------------------------------------------------------------------------
// Kernel 3 (fused routing pass): 16 rows per wave (8192 waves, 2x TLP),
// distance-2 rolling prefetch (8KB/wave in flight), b[] preloaded once.
// ---------------------------------------------------------------------------
__global__ __launch_bounds__(256) void kbv_kernel(
    const __half* __restrict__ e, float* __restrict__ b,
    const float* __restrict__ c_buf, float* __restrict__ u_part,
    float* __restrict__ den_part) {
  const int w = threadIdx.x >> 6;
  const int lane = threadIdx.x & 63;
  const int wave_g = blockIdx.x * 4 + w;   // 0..8191
  const int cap = wave_g >> 7;             // 128 chunks per capsule
  const int chunk = wave_g & 127;
  const int r0 = cap * 2048 + chunk * 16;  // 16 rows per wave

  float c8[8];
  {
    const float4* cp = (const float4*)(c_buf + cap * HDIM + lane * 8);
    float4 ca = cp[0], cb = cp[1];
    c8[0] = ca.x; c8[1] = ca.y; c8[2] = ca.z; c8[3] = ca.w;
    c8[4] = cb.x; c8[5] = cb.y; c8[6] = cb.z; c8[7] = cb.w;
  }
  const float bline = b[r0 + (lane & 15)];  // all 16 b values, once
  float u8[8] = {0, 0, 0, 0, 0, 0, 0, 0};
  float den = 0.f;

  union U { int4 v; __half hh[8]; };
  U buf[3][4];
  const __half* yb = e + (size_t)r0 * HDIM + lane * 8;
#pragma unroll
  for (int j = 0; j < 4; ++j) buf[0][j].v = *(const int4*)(yb + (size_t)j * HDIM);
#pragma unroll
  for (int j = 0; j < 4; ++j)
    buf[1][j].v = *(const int4*)(yb + (size_t)(4 + j) * HDIM);

#pragma unroll
  for (int g = 0; g < 4; ++g) {
    const int rg = r0 + g * 4;
    if (g < 2) {
#pragma unroll
      for (int j = 0; j < 4; ++j)
        buf[(g + 2) % 3][j].v =
            *(const int4*)(yb + (size_t)((g + 2) * 4 + j) * HDIM);
    }
    const U* cur = buf[g % 3];
    float dot[4];
#pragma unroll
    for (int j = 0; j < 4; ++j) {
      float d = 0.f;
#pragma unroll
      for (int k = 0; k < 8; ++k) d += __half2float(cur[j].hh[k]) * c8[k];
      dot[j] = d;
    }
#pragma unroll
    for (int s = 1; s < 64; s <<= 1) {
#pragma unroll
      for (int j = 0; j < 4; ++j) dot[j] += __shfl_xor(dot[j], s, 64);
    }
#pragma unroll
    for (int j = 0; j < 4; ++j) {
      float bn = __shfl(bline, g * 4 + j, 64) + dot[j];
      if (lane == 0) b[rg + j] = bn;
      float wj = __expf(bn);  // |b| small: no max-subtraction needed
      den += wj;
#pragma unroll
      for (int k = 0; k < 8; ++k) u8[k] += wj * __half2float(cur[j].hh[k]);
    }
  }

  // intra-block reduction: 4 waves -> one partial per block
  __shared__ float lred[4][512];
  __shared__ float ldn[4];
#pragma unroll
  for (int k = 0; k < 8; ++k) lred[w][lane * 8 + k] = u8[k];
  if (lane == 0) ldn[w] = den;
  __syncthreads();
  const int t = threadIdx.x;
  const int blkc = blockIdx.x & 31;  // 32 blocks per capsule
#pragma unroll
  for (int hh = 0; hh < 2; ++hh) {
    int h = hh * 256 + t;
    float v = lred[0][h] + lred[1][h] + lred[2][h] + lred[3][h];
    u_part[((size_t)cap * 32 + blkc) * HDIM + h] = v;
  }
  if (t == 0)
    den_part[cap * 32 + blkc] = ldn[0] + ldn[1] + ldn[2] + ldn[3];
}

// ---------------------------------------------------------------------------
// Kernel 4: per capsule: v = (sum_chunk u_part)/(sum den_part); c = squash(v)
// nch = number of valid chunks (16 after gemm-it1, 32 after kbv)
// ---------------------------------------------------------------------------
__global__ __launch_bounds__(512) void kcsq_kernel(
    const float* __restrict__ u_part, const float* __restrict__ den_part,
    float* __restrict__ out, int nch) {
  const int cap = blockIdx.x;
  const int t = threadIdx.x;
  __shared__ float red[512];
  __shared__ float sden;

  if (t < nch) red[t] = den_part[cap * 32 + t];
  __syncthreads();
  if (t == 0) {
    float s = 0.f;
    for (int i = 0; i < nch; ++i) s += red[i];
    sden = s;
  }
  __syncthreads();
  const float den = sden;

  float v = 0.f;
  const float* up = u_part + (size_t)cap * 32 * HDIM + t;
  for (int ch = 0; ch < nch; ++ch) v += up[ch * HDIM];
  v /= den;

  __syncthreads();
  red[t] = v * v;
  __syncthreads();
  for (int s = 256; s > 0; s >>= 1) {
    if (t < s) red[t] += red[t + s];
    __syncthreads();
  }
  const float sqv = red[0];
  const float scv = sqv / ((1.f + sqv) * sqrtf(sqv + 1e-7f));
  out[cap * HDIM + t] = v * scv;
}

// ---------------------------------------------------------------------------
extern "C" void kernel_launch(void* const* d_in, const int* in_sizes, int n_in,
                              void* d_out, int out_size, void* d_ws,
                              size_t ws_size, hipStream_t stream) {
  const float* x = (const float*)d_in[0];     // [131072,512]
  const float* W = (const float*)d_in[1];     // [512,512]
  const float* bias = (const float*)d_in[2];  // [512]
  float* out = (float*)d_out;                 // [64,512]
  char* ws = (char*)d_ws;

  __half* e = (__half*)ws;                              // 134217728 B
  float* b = (float*)(ws + (size_t)134217728);          // 131072 f
  float* c_buf = b + 131072;                            // 32768 f
  float* u_part = c_buf + 32768;                        // 64*32*512 f
  float* den_part = u_part + (size_t)64 * 32 * 512;     // 2048 f
  _Float16* wf = (_Float16*)(den_part + 2048);          // 262144 h

  (void)hipMemsetAsync(b, 0, (size_t)131072 * sizeof(float), stream);

  prep_w_kernel<<<256, 256, 0, stream>>>(W, wf);
  gemm_kernel<<<1024, 512, 0, stream>>>(x, wf, bias, e, u_part, den_part);

  // iteration 1 (uniform softmax) was fused into the GEMM epilogue
  kcsq_kernel<<<64, 512, 0, stream>>>(u_part, den_part, c_buf, 16);
  kbv_kernel<<<2048, 256, 0, stream>>>(e, b, c_buf, u_part, den_part);
  kcsq_kernel<<<64, 512, 0, stream>>>(u_part, den_part, c_buf, 32);
  kbv_kernel<<<2048, 256, 0, stream>>>(e, b, c_buf, u_part, den_part);
  kcsq_kernel<<<64, 512, 0, stream>>>(u_part, den_part, out, 32);
}

// Round 4
// 469.893 us; speedup vs baseline: 1.0598x; 1.0598x over previous
//
#include <hip/hip_runtime.h>
#include <hip/hip_fp16.h>

// Problem constants: C=64, S=2048, H=512; rows = C*S = 131072
#define HDIM 512

typedef __fp16 fp16x2 __attribute__((ext_vector_type(2)));
typedef _Float16 h8 __attribute__((ext_vector_type(8)));
typedef __attribute__((ext_vector_type(4))) float floatx4;

// raw barrier: LDS-visibility only, no vmem drain (unlike __syncthreads)
__device__ __forceinline__ void lds_barrier() {
  asm volatile("s_waitcnt lgkmcnt(0)\n\ts_barrier" ::: "memory");
}
__device__ __forceinline__ void issue_fence() {  // pin vm-issue order
  asm volatile("" ::: "memory");
}

// ---------------------------------------------------------------------------
// Kernel 1: W fp32 -> fp16 (RTE)
// ---------------------------------------------------------------------------
__global__ __launch_bounds__(256) void prep_w_kernel(
    const float* __restrict__ W, _Float16* __restrict__ wf) {
  int i = (blockIdx.x * 256 + threadIdx.x) * 4;
  float4 f = *(const float4*)(W + i);
  wf[i + 0] = (_Float16)f.x;
  wf[i + 1] = (_Float16)f.y;
  wf[i + 2] = (_Float16)f.z;
  wf[i + 3] = (_Float16)f.w;
}

// ---------------------------------------------------------------------------
// Kernel 2: fused GEMM — EXACT round-2-proven structure (162 us, passed):
// BM=128 x BN=512, BK=32, 8 waves, 4-deep W ring via global_load_lds,
// dma+x issued before the barrier at distance 2. Only changes vs round 2:
// (a) swizzle pair reverted to the round-1 form (3.1M vs 7.3M conflicts),
// (b) epilogue writes u_gemm[cap][16][512] (iteration-1 partial col-sums;
//     den after iter 1 is exactly 2048, no buffer needed).
// ---------------------------------------------------------------------------
#define XS_H (128 * 40)  // x tile, stride padded 32->40 halves
#define WS_H (512 * 32)  // w tile halves per buffer

__device__ __forceinline__ void issue_w_dma(const _Float16* __restrict__ wf,
                                            _Float16* dst, int kt, int tid,
                                            int widx) {
#pragma unroll
  for (int q = 0; q < 4; ++q) {
    int idx = q * 512 + tid;
    int n = idx >> 2;                      // W row (output col), 0..511
    int src = (idx & 3) ^ ((n >> 1) & 3);  // round-1 source-side XOR swizzle
    size_t goff = (size_t)n * HDIM + kt * 32 + src * 8;
    __builtin_amdgcn_global_load_lds(
        (const __attribute__((address_space(1))) void*)(wf + goff),
        (__attribute__((address_space(3))) void*)(dst +
                                                  (q * 512 + widx * 64) * 8),
        16, 0, 0);
  }
}

__global__ __launch_bounds__(512, 2) void gemm_kernel(
    const float* __restrict__ x, const _Float16* __restrict__ wf,
    const float* __restrict__ bias, __half* __restrict__ e,
    float* __restrict__ u_gemm) {
  __shared__ __align__(16) _Float16 smem[2 * XS_H + 4 * WS_H];  // 151552 B
  _Float16* xs[2] = {smem, smem + XS_H};
  _Float16* wsm = smem + 2 * XS_H;

  const int tid = threadIdx.x;
  const int lane = tid & 63;
  const int widx = tid >> 6;       // 0..7
  const int wave_m = widx >> 2;    // 0..1
  const int wave_n = widx & 3;     // 0..3
  const int lrow = lane & 15, quad = lane >> 4;

  const int bid = blockIdx.x;      // 1024 blocks, 128 rows each
  const int row0 = bid * 128;

  const int xrow = tid >> 2;       // 0..127
  const int xcg = tid & 3;         // 8-float chunk within 32-float K-tile
  const float* xbase = x + (size_t)(row0 + xrow) * HDIM + xcg * 8;

  floatx4 acc[4][8];
#pragma unroll
  for (int i = 0; i < 4; ++i)
#pragma unroll
    for (int j = 0; j < 8; ++j) acc[i][j] = (floatx4){0.f, 0.f, 0.f, 0.f};

  float4 xr[2][2];

  // prologue: dma_0, x_0, dma_1, x_1 (dma before x => drained by x's wait)
  issue_w_dma(wf, wsm + 0 * WS_H, 0, tid, widx);
  issue_fence();
  xr[0][0] = *(const float4*)xbase;
  xr[0][1] = *(const float4*)(xbase + 4);
  issue_fence();
  issue_w_dma(wf, wsm + 1 * WS_H, 1, tid, widx);
  issue_fence();
  xr[1][0] = *(const float4*)(xbase + 32);
  xr[1][1] = *(const float4*)(xbase + 36);
  issue_fence();

  const int chunkB = quad ^ ((lrow >> 1) & 3);  // round-1 read-side swizzle

#pragma unroll
  for (int t = 0; t < 16; ++t) {
    // ---- stage x_t (fp32->fp16); compiler waits x_t here, draining dma_t
    {
      float4 a0 = xr[t & 1][0], a1 = xr[t & 1][1];
      union { h8 v8; fp16x2 v2[4]; } u;
      u.v2[0] = __builtin_amdgcn_cvt_pkrtz(a0.x, a0.y);
      u.v2[1] = __builtin_amdgcn_cvt_pkrtz(a0.z, a0.w);
      u.v2[2] = __builtin_amdgcn_cvt_pkrtz(a1.x, a1.y);
      u.v2[3] = __builtin_amdgcn_cvt_pkrtz(a1.z, a1.w);
      *(h8*)&xs[t & 1][xrow * 40 + xcg * 8] = u.v8;
    }
    // ---- issue next loads BEFORE the barrier (dma older than x)
    if (t <= 13) {
      issue_w_dma(wf, wsm + ((t + 2) & 3) * WS_H, t + 2, tid, widx);
      issue_fence();
      const float* gp = xbase + (t + 2) * 32;
      xr[t & 1][0] = *(const float4*)gp;
      xr[t & 1][1] = *(const float4*)(gp + 4);
      issue_fence();
    }
    lds_barrier();  // xs(t) visible AND all waves' dma_t drained (via stage)
    // ---- compute
    const _Float16* xsr = xs[t & 1];
    const _Float16* wcur = wsm + (t & 3) * WS_H;
    h8 a[4], bh[8];
#pragma unroll
    for (int mt = 0; mt < 4; ++mt)
      a[mt] = *(const h8*)&xsr[(wave_m * 64 + mt * 16 + lrow) * 40 + quad * 8];
#pragma unroll
    for (int nt = 0; nt < 8; ++nt)
      bh[nt] =
          *(const h8*)&wcur[(wave_n * 128 + nt * 16 + lrow) * 32 + chunkB * 8];
    __builtin_amdgcn_s_setprio(1);
#pragma unroll
    for (int mt = 0; mt < 4; ++mt)
#pragma unroll
      for (int nt = 0; nt < 8; ++nt)
        acc[mt][nt] = __builtin_amdgcn_mfma_f32_16x16x32_f16(
            a[mt], bh[nt], acc[mt][nt], 0, 0, 0);
    __builtin_amdgcn_s_setprio(0);
  }

  // ---- epilogue: squash + e-write + iteration-1 partials (no atomics) ----
  float* sqp = (float*)smem;        // [4][128]  (reuses xs[0] region)
  float* scs = (float*)smem + 512;  // [128]
  float* upl = (float*)smem + 640;  // [2][512]

  float bias_v[8];
  int colg[8];
#pragma unroll
  for (int nt = 0; nt < 8; ++nt) {
    colg[nt] = wave_n * 128 + nt * 16 + lrow;
    bias_v[nt] = bias[colg[nt]];
  }
#pragma unroll
  for (int mt = 0; mt < 4; ++mt) {
#pragma unroll
    for (int r = 0; r < 4; ++r) {
      float s = 0.f;
#pragma unroll
      for (int nt = 0; nt < 8; ++nt) {
        float yv = acc[mt][nt][r] + bias_v[nt];
        s += yv * yv;
      }
      s += __shfl_xor(s, 1, 64);
      s += __shfl_xor(s, 2, 64);
      s += __shfl_xor(s, 4, 64);
      s += __shfl_xor(s, 8, 64);
      if (lrow == 0)
        sqp[wave_n * 128 + wave_m * 64 + mt * 16 + quad * 4 + r] = s;
    }
  }
  lds_barrier();
  if (tid < 128) {
    float s = sqp[tid] + sqp[128 + tid] + sqp[256 + tid] + sqp[384 + tid];
    scs[tid] = s / ((1.f + s) * sqrtf(s + 1e-7f));
  }
  lds_barrier();

  float up[8] = {0.f, 0.f, 0.f, 0.f, 0.f, 0.f, 0.f, 0.f};
#pragma unroll
  for (int mt = 0; mt < 4; ++mt) {
#pragma unroll
    for (int r = 0; r < 4; ++r) {
      int row_local = wave_m * 64 + mt * 16 + quad * 4 + r;
      float scv = scs[row_local];
      __half* erow = e + (size_t)(row0 + row_local) * HDIM;
#pragma unroll
      for (int nt = 0; nt < 8; ++nt) {
        float ev = (acc[mt][nt][r] + bias_v[nt]) * scv;
        erow[colg[nt]] = __float2half(ev);
        up[nt] += ev;
      }
    }
  }
#pragma unroll
  for (int nt = 0; nt < 8; ++nt) {
    float v = up[nt];
    v += __shfl_xor(v, 16, 64);
    v += __shfl_xor(v, 32, 64);
    if (quad == 0) upl[wave_m * 512 + colg[nt]] = v;
  }
  lds_barrier();
  // u_gemm[cap][chunk][col]; 16 chunks (128-row blocks) per capsule
  u_gemm[(size_t)(bid >> 4) * 16 * HDIM + (size_t)(bid & 15) * HDIM + tid] =
      upl[tid] + upl[512 + tid];
}

// ---------------------------------------------------------------------------
// Kernel 3: one routing iteration, sync via kernel boundaries only.
// Phase R: every block redundantly computes c for its capsule from the 16
// partials of the previous launch (32 KB, L2-resident — no grid.sync, no
// separate kcsq dispatch). Phase B: re-read e rows, update b, emit partials.
// FIRST: den = 2048 exactly and b is write-only (bn = dot); second launch
// reads b and skips the dead write.
// ---------------------------------------------------------------------------
template <bool FIRST>
__global__ __launch_bounds__(256, 4) void route_iter_kernel(
    const __half* __restrict__ e, const float* __restrict__ u_in,
    const float* __restrict__ den_in, float* __restrict__ b,
    float* __restrict__ u_out, float* __restrict__ den_out) {
  const int tid = threadIdx.x;
  const int w = tid >> 6;
  const int lane = tid & 63;
  const int bid = blockIdx.x;
  const int cap = bid >> 4;  // 16 blocks per capsule
  const int r0 = bid * 128;

  __shared__ float csh[512];
  __shared__ float red[256];
  __shared__ float lred[4][512];
  __shared__ float ldn[4];
  __shared__ float sden;

  // ---- phase R: c = squash(sum u / den) for this block's capsule ----
  float v0 = 0.f, v1 = 0.f;
  {
    const float* upb = u_in + (size_t)cap * 16 * HDIM;
#pragma unroll
    for (int ch = 0; ch < 16; ++ch) {
      v0 += upb[ch * HDIM + tid];
      v1 += upb[ch * HDIM + tid + 256];
    }
  }
  float den;
  if (FIRST) {
    den = 2048.f;  // sum of exp(0) over S, exactly
  } else {
    red[tid] = (tid < 16) ? den_in[cap * 16 + tid] : 0.f;
    __syncthreads();
    if (tid == 0) {
      float s = 0.f;
#pragma unroll
      for (int i = 0; i < 16; ++i) s += red[i];
      sden = s;
    }
    __syncthreads();
    den = sden;
    __syncthreads();
  }
  v0 /= den;
  v1 /= den;
  red[tid] = v0 * v0 + v1 * v1;
  __syncthreads();
  for (int s = 128; s > 0; s >>= 1) {
    if (tid < s) red[tid] += red[tid + s];
    __syncthreads();
  }
  const float sqv = red[0];
  const float scv = sqv / ((1.f + sqv) * sqrtf(sqv + 1e-7f));
  csh[tid] = v0 * scv;
  csh[tid + 256] = v1 * scv;
  __syncthreads();

  // ---- phase B: b += e.c ; partial softmax-weighted sums ----
  float c8[8];
#pragma unroll
  for (int k = 0; k < 8; ++k) c8[k] = csh[lane * 8 + k];
  float u8[8] = {0, 0, 0, 0, 0, 0, 0, 0};
  float den_w = 0.f;

  union U { int4 v; __half hh[8]; };
  U cur[4], nxt[4];
  const __half* yb = e + (size_t)(r0 + w * 32) * HDIM + lane * 8;
#pragma unroll
  for (int j = 0; j < 4; ++j) cur[j].v = *(const int4*)(yb + (size_t)j * HDIM);

  for (int g = 0; g < 8; ++g) {
    if (g < 7) {
#pragma unroll
      for (int j = 0; j < 4; ++j)
        nxt[j].v = *(const int4*)(yb + (size_t)(g * 4 + 4 + j) * HDIM);
    }
    float dot[4];
#pragma unroll
    for (int j = 0; j < 4; ++j) {
      float d = 0.f;
#pragma unroll
      for (int k = 0; k < 8; ++k) d += __half2float(cur[j].hh[k]) * c8[k];
      dot[j] = d;
    }
#pragma unroll
    for (int s = 1; s < 64; s <<= 1) {
#pragma unroll
      for (int j = 0; j < 4; ++j) dot[j] += __shfl_xor(dot[j], s, 64);
    }
#pragma unroll
    for (int j = 0; j < 4; ++j) {
      const int rl = w * 32 + g * 4 + j;  // row within block
      float bn = FIRST ? dot[j] : (b[r0 + rl] + dot[j]);
      if (FIRST && lane == 0) b[r0 + rl] = bn;  // launch-2 write is dead
      float wj = __expf(bn);  // |b| small: no max-subtraction needed
      den_w += wj;
#pragma unroll
      for (int k = 0; k < 8; ++k) u8[k] += wj * __half2float(cur[j].hh[k]);
    }
#pragma unroll
    for (int j = 0; j < 4; ++j) cur[j] = nxt[j];
  }

  // intra-block reduction: 4 waves -> one partial per block
#pragma unroll
  for (int k = 0; k < 8; ++k) lred[w][lane * 8 + k] = u8[k];
  if (lane == 0) ldn[w] = den_w;
  __syncthreads();
  float* ur = u_out + (size_t)cap * 16 * HDIM + (size_t)(bid & 15) * HDIM;
#pragma unroll
  for (int hh = 0; hh < 2; ++hh) {
    int h = hh * 256 + tid;
    ur[h] = lred[0][h] + lred[1][h] + lred[2][h] + lred[3][h];
  }
  if (tid == 0)
    den_out[cap * 16 + (bid & 15)] = ldn[0] + ldn[1] + ldn[2] + ldn[3];
}

// ---------------------------------------------------------------------------
// Kernel 4: final phase R only: c3 = squash(sum u / sum den) -> out
// ---------------------------------------------------------------------------
__global__ __launch_bounds__(512) void route_final_kernel(
    const float* __restrict__ u_in, const float* __restrict__ den_in,
    float* __restrict__ out) {
  const int cap = blockIdx.x;
  const int t = threadIdx.x;
  __shared__ float red[512];
  __shared__ float sden;

  red[t] = (t < 16) ? den_in[cap * 16 + t] : 0.f;
  __syncthreads();
  if (t == 0) {
    float s = 0.f;
#pragma unroll
    for (int i = 0; i < 16; ++i) s += red[i];
    sden = s;
  }
  __syncthreads();
  const float den = sden;

  float v = 0.f;
  const float* up = u_in + (size_t)cap * 16 * HDIM + t;
#pragma unroll
  for (int ch = 0; ch < 16; ++ch) v += up[ch * HDIM];
  v /= den;

  __syncthreads();
  red[t] = v * v;
  __syncthreads();
  for (int s = 256; s > 0; s >>= 1) {
    if (t < s) red[t] += red[t + s];
    __syncthreads();
  }
  const float sqv = red[0];
  const float scv = sqv / ((1.f + sqv) * sqrtf(sqv + 1e-7f));
  out[cap * HDIM + t] = v * scv;
}

// ---------------------------------------------------------------------------
extern "C" void kernel_launch(void* const* d_in, const int* in_sizes, int n_in,
                              void* d_out, int out_size, void* d_ws,
                              size_t ws_size, hipStream_t stream) {
  const float* x = (const float*)d_in[0];     // [131072,512]
  const float* W = (const float*)d_in[1];     // [512,512]
  const float* bias = (const float*)d_in[2];  // [512]
  float* out = (float*)d_out;                 // [64,512]
  char* ws = (char*)d_ws;

  __half* e = (__half*)ws;                            // 134217728 B
  float* u_gemm = (float*)(ws + (size_t)134217728);   // 64*16*512 f
  float* u_a = u_gemm + (size_t)64 * 16 * 512;        // 64*16*512 f
  float* u_b = u_a + (size_t)64 * 16 * 512;           // 64*16*512 f
  float* den_a = u_b + (size_t)64 * 16 * 512;         // 1024 f
  float* den_b = den_a + 1024;                        // 1024 f
  float* b = den_b + 1024;                            // 131072 f
  _Float16* wf = (_Float16*)(b + 131072);             // 262144 h

  prep_w_kernel<<<256, 256, 0, stream>>>(W, wf);
  gemm_kernel<<<1024, 512, 0, stream>>>(x, wf, bias, e, u_gemm);

  // iteration 1's reduction was fused into the GEMM epilogue (b=0 uniform)
  route_iter_kernel<true><<<1024, 256, 0, stream>>>(e, u_gemm, nullptr, b,
                                                    u_a, den_a);
  route_iter_kernel<false><<<1024, 256, 0, stream>>>(e, u_a, den_a, b,
                                                     u_b, den_b);
  route_final_kernel<<<64, 512, 0, stream>>>(u_b, den_b, out);
}